// Round 1
// baseline (2213.931 us; speedup 1.0000x reference)
//
#include <hip/hip_runtime.h>
#include <cstdint>

// ============================================================================
// TripleAdaptiveQuantizerV5 — round 1: correctness-first implementation.
//
// Pipeline:
//   K0: ss scales (f32-exact replication of _grad_scale) + threefry split keys
//   K1a/K1b: hp_mean[b,k] = mean over L of h_power (deterministic 2-stage, f64)
//   K2: per-(b,l) block (64 lanes = 64 k's): features (f64) -> MLP (f32, full
//       unroll, scalar-cached weights) -> gumbel scores (threefry bit-exact,
//       f32 logs) -> argmax with top-2 margin check; margin < 3e-4 => full f64
//       recompute (rare).  Writes w_y/w_H/w_demod one-hots + all bits outputs.
//   K3/K4/K5: LSQ quantization of H/v/y, replicating reference f32 ops
//       (IEEE div, clip, rintf=RNE, mul). Selection index recovered from the
//       already-written *_bits outputs (saves workspace).
//
// RNG: modern JAX (threefry_partitionable=True): bits(e) = o0^o1 of
//      threefry2x32(key, (0,e)); split(key,n) foldlike: child i = full output
//      pair of threefry2x32(key, (0,i)).  Legacy mode kept under the #define.
// ============================================================================

#define JAX_PARTITIONABLE 1

constexpr int B_DIM = 64, L_DIM = 256, N_DIM = 8, K_DIM = 64;
constexpr int BL = B_DIM * L_DIM;  // 16384

// Output offsets (floats)
constexpr long long O_vq  = 0;
constexpr long long O_Hq  = 2097152;
constexpr long long O_yq  = 18874368;
constexpr long long O_eb  = 19136512;
constexpr long long O_wy  = 20185088;
constexpr long long O_wH  = 20283392;
constexpr long long O_wd  = 26574848;
constexpr long long O_yba = 32866304;
constexpr long long O_Hbl = 32882688;
constexpr long long O_dbl = 33931264;

#define MARGIN_THETA 3e-4

// ---------------------------------------------------------------- threefry
__device__ __forceinline__ uint32_t rotl32(uint32_t v, int d) {
  return (v << d) | (v >> (32 - d));
}

__device__ __forceinline__ void threefry2x32(uint32_t k0, uint32_t k1,
                                             uint32_t x0, uint32_t x1,
                                             uint32_t& o0, uint32_t& o1) {
  const uint32_t ks2 = k0 ^ k1 ^ 0x1BD11BDAu;
  x0 += k0; x1 += k1;
  x0 += x1; x1 = rotl32(x1, 13); x1 ^= x0;
  x0 += x1; x1 = rotl32(x1, 15); x1 ^= x0;
  x0 += x1; x1 = rotl32(x1, 26); x1 ^= x0;
  x0 += x1; x1 = rotl32(x1, 6);  x1 ^= x0;
  x0 += k1; x1 += ks2 + 1u;
  x0 += x1; x1 = rotl32(x1, 17); x1 ^= x0;
  x0 += x1; x1 = rotl32(x1, 29); x1 ^= x0;
  x0 += x1; x1 = rotl32(x1, 16); x1 ^= x0;
  x0 += x1; x1 = rotl32(x1, 24); x1 ^= x0;
  x0 += ks2; x1 += k0 + 2u;
  x0 += x1; x1 = rotl32(x1, 13); x1 ^= x0;
  x0 += x1; x1 = rotl32(x1, 15); x1 ^= x0;
  x0 += x1; x1 = rotl32(x1, 26); x1 ^= x0;
  x0 += x1; x1 = rotl32(x1, 6);  x1 ^= x0;
  x0 += k0; x1 += k1 + 3u;
  x0 += x1; x1 = rotl32(x1, 17); x1 ^= x0;
  x0 += x1; x1 = rotl32(x1, 29); x1 ^= x0;
  x0 += x1; x1 = rotl32(x1, 16); x1 ^= x0;
  x0 += x1; x1 = rotl32(x1, 24); x1 ^= x0;
  x0 += k1; x1 += ks2 + 4u;
  x0 += x1; x1 = rotl32(x1, 13); x1 ^= x0;
  x0 += x1; x1 = rotl32(x1, 15); x1 ^= x0;
  x0 += x1; x1 = rotl32(x1, 26); x1 ^= x0;
  x0 += x1; x1 = rotl32(x1, 6);  x1 ^= x0;
  x0 += ks2; x1 += k0 + 5u;
  o0 = x0; o1 = x1;
}

// random 32-bit word for flat element e of an array of `size` elements
__device__ __forceinline__ uint32_t jax_randbits(uint32_t k0, uint32_t k1,
                                                 uint32_t e, uint32_t size) {
#if JAX_PARTITIONABLE
  (void)size;
  uint32_t o0, o1;
  threefry2x32(k0, k1, 0u, e, o0, o1);
  return o0 ^ o1;
#else
  const uint32_t half = size >> 1;
  uint32_t o0, o1;
  if (e < half) { threefry2x32(k0, k1, e, e + half, o0, o1); return o0; }
  threefry2x32(k0, k1, e - half, e, o0, o1); return o1;
#endif
}

// exact f32 replication of jax.random.uniform(minval=1e-10, maxval=1.0)
__device__ __forceinline__ float bits_to_unif(uint32_t bits) {
  float f = __uint_as_float((bits >> 9) | 0x3f800000u) - 1.0f;
  return fmaxf(1e-10f, f + 1e-10f);  // (maxval-minval) rounds to 1.0f
}

// ---------------------------------------------------------------- helpers
__device__ __forceinline__ double wave_sum_f64(double x) {
#pragma unroll
  for (int off = 32; off > 0; off >>= 1) x += __shfl_xor(x, off);
  return x;
}

__device__ __forceinline__ void argmax_gap6(const double* s, int& arg, double& gap) {
  int a = 0;
#pragma unroll
  for (int j = 1; j < 6; ++j) if (s[j] > s[a]) a = j;
  double second = -1e300;
#pragma unroll
  for (int j = 0; j < 6; ++j) if (j != a && s[j] > second) second = s[j];
  arg = a; gap = s[a] - second;
}

__device__ __forceinline__ float idx_to_bits(int i) {
  return (float)((i < 4) ? 2 * (i + 1) : (i == 4 ? 12 : 16));
}

// fully-unrolled 64-wide relu layer; weights are wave-uniform -> scalar loads
template <int NIN>
__device__ __forceinline__ void layer_relu64(const float* in,
                                             const float* __restrict__ W,
                                             const float* __restrict__ bias,
                                             float* out) {
#pragma unroll
  for (int jt = 0; jt < 16; ++jt) {
    float a0 = bias[4 * jt + 0], a1 = bias[4 * jt + 1];
    float a2 = bias[4 * jt + 2], a3 = bias[4 * jt + 3];
    const float* r0 = W + (4 * jt + 0) * NIN;
    const float* r1 = W + (4 * jt + 1) * NIN;
    const float* r2 = W + (4 * jt + 2) * NIN;
    const float* r3 = W + (4 * jt + 3) * NIN;
#pragma unroll
    for (int i = 0; i < NIN; ++i) {
      const float x = in[i];
      a0 = fmaf(x, r0[i], a0);
      a1 = fmaf(x, r1[i], a1);
      a2 = fmaf(x, r2[i], a2);
      a3 = fmaf(x, r3[i], a3);
    }
    out[4 * jt + 0] = fmaxf(a0, 0.0f);
    out[4 * jt + 1] = fmaxf(a1, 0.0f);
    out[4 * jt + 2] = fmaxf(a2, 0.0f);
    out[4 * jt + 3] = fmaxf(a3, 0.0f);
  }
}

__device__ __forceinline__ void head6(const float* in, const float* __restrict__ W,
                                      const float* __restrict__ bias, float* out) {
#pragma unroll
  for (int r = 0; r < 6; ++r) {
    float a = bias[r];
    const float* row = W + r * 64;
#pragma unroll
    for (int i = 0; i < 64; ++i) a = fmaf(in[i], row[i], a);
    out[r] = a;
  }
}

// rare-path f64 MLP: rolled loops + local arrays -> scratch, keeps VGPR count low
__device__ __noinline__ void mlp_f64_fallback(
    const double* __restrict__ feat,
    const float* __restrict__ w1, const float* __restrict__ b1,
    const float* __restrict__ w2, const float* __restrict__ b2,
    const float* __restrict__ w3, const float* __restrict__ b3,
    const float* __restrict__ wy, const float* __restrict__ by,
    const float* __restrict__ wh, const float* __restrict__ bh,
    const float* __restrict__ wd, const float* __restrict__ bd,
    double* __restrict__ ly, double* __restrict__ lh, double* __restrict__ ld) {
  double h1[64], h2[64], h3[64];
#pragma unroll 1
  for (int j = 0; j < 64; ++j) {
    double a = (double)b1[j];
#pragma unroll 1
    for (int i = 0; i < 9; ++i) a = fma(feat[i], (double)w1[j * 9 + i], a);
    h1[j] = a > 0.0 ? a : 0.0;
  }
#pragma unroll 1
  for (int j = 0; j < 64; ++j) {
    double a = (double)b2[j];
#pragma unroll 1
    for (int i = 0; i < 64; ++i) a = fma(h1[i], (double)w2[j * 64 + i], a);
    h2[j] = a > 0.0 ? a : 0.0;
  }
#pragma unroll 1
  for (int j = 0; j < 64; ++j) {
    double a = (double)b3[j];
#pragma unroll 1
    for (int i = 0; i < 64; ++i) a = fma(h2[i], (double)w3[j * 64 + i], a);
    h3[j] = a > 0.0 ? a : 0.0;
  }
#pragma unroll 1
  for (int r = 0; r < 6; ++r) {
    double a = (double)by[r], c = (double)bh[r], d = (double)bd[r];
#pragma unroll 1
    for (int i = 0; i < 64; ++i) {
      const double x = h3[i];
      a = fma(x, (double)wy[r * 64 + i], a);
      c = fma(x, (double)wh[r * 64 + i], c);
      d = fma(x, (double)wd[r * 64 + i], d);
    }
    ly[r] = a; lh[r] = c; ld[r] = d;
  }
}

// ---------------------------------------------------------------- K0: ss + keys
__global__ void k0_setup(const float* __restrict__ sy, const float* __restrict__ sH,
                         const float* __restrict__ sd, float* __restrict__ ss,
                         uint32_t* __restrict__ keys) {
  const int t = threadIdx.x;
  if (t < 18) {
    const int tensor = t / 6, i = t % 6;
    const int qp_[6] = {1, 7, 31, 127, 2047, 32767};
    const long long sizes[3] = {262144LL, 16777216LL, 2097152LL};  // y, H, v
    const float* sarr = tensor == 0 ? sy : (tensor == 1 ? sH : sd);
    // g computed in python f64, cast to f32 at use site (weak-typed scalar)
    const double g64 = 1.0 / sqrt((double)(sizes[tensor] * (long long)qp_[i]));
    const float g32 = (float)g64;
    const float s = sarr[i];
    const float t1 = s * g32;
    ss[t] = t1 + (s - t1);  // _grad_scale forward, exact f32 sequence
  }
#if JAX_PARTITIONABLE
  if (t >= 32 && t < 35) {  // foldlike split: child i = tf(key,(0,i)) pair
    uint32_t o0, o1;
    threefry2x32(0u, 42u, 0u, (uint32_t)(t - 32), o0, o1);
    keys[(t - 32) * 2 + 0] = o0;
    keys[(t - 32) * 2 + 1] = o1;
  }
#else
  if (t == 32) {  // original split: bits = tf(key, iota(6)) halves-concat
    uint32_t a0, b0, a1, b1, a2, b2;
    threefry2x32(0u, 42u, 0u, 3u, a0, b0);
    threefry2x32(0u, 42u, 1u, 4u, a1, b1);
    threefry2x32(0u, 42u, 2u, 5u, a2, b2);
    keys[0] = a0; keys[1] = a1;  // g1
    keys[2] = a2; keys[3] = b0;  // g2
    keys[4] = b1; keys[5] = b2;  // g3
  }
#endif
}

// ---------------------------------------------------------------- K1: hp_mean
__global__ __launch_bounds__(128) void k1a_hpower_partial(
    const float* __restrict__ Hm, double* __restrict__ partial) {
  const int blk = blockIdx.x;       // 512 = 64 b * 8 l-chunks
  const int b = blk >> 3, lc = blk & 7;
  const int t = threadIdx.x;        // 128 = (k,c)
  const float* base = Hm + (size_t)(b * 256 + lc * 32) * 1024;
  double acc = 0.0;
  for (int l = 0; l < 32; ++l) {
#pragma unroll
    for (int n = 0; n < 8; ++n) {
      const float x = base[(size_t)l * 1024 + n * 128 + t];
      acc = fma((double)x, (double)x, acc);
    }
  }
  const double other = __shfl_xor(acc, 1);
  if ((t & 1) == 0) partial[(size_t)blk * 64 + (t >> 1)] = acc + other;
}

__global__ void k1b_hpmean(const double* __restrict__ partial,
                           double* __restrict__ hp_mean) {
  const int id = blockIdx.x * blockDim.x + threadIdx.x;  // 4096 = b*64+k
  if (id >= 4096) return;
  const int b = id >> 6, k = id & 63;
  double s = 0.0;
#pragma unroll
  for (int lc = 0; lc < 8; ++lc) s += partial[(size_t)(b * 8 + lc) * 64 + k];
  hp_mean[id] = s * (1.0 / 256.0);
}

// ---------------------------------------------------------------- K2: main
__global__ __launch_bounds__(64) void k2_main(
    const float* __restrict__ v, const float* __restrict__ Hm,
    const float* __restrict__ y, const float* __restrict__ snr,
    const float* __restrict__ w1, const float* __restrict__ b1,
    const float* __restrict__ w2, const float* __restrict__ b2,
    const float* __restrict__ w3, const float* __restrict__ b3,
    const float* __restrict__ wy, const float* __restrict__ by,
    const float* __restrict__ wh, const float* __restrict__ bh,
    const float* __restrict__ wd, const float* __restrict__ bd,
    const double* __restrict__ hp_mean, const uint32_t* __restrict__ keys,
    float* __restrict__ out) {
  const int m = blockIdx.x;   // b*L + l
  const int k = threadIdx.x;  // 0..63
  const int b = m >> 8;       // L = 256

  // ---- features (f64 base values kept for the fallback) ----
  double hp = 0.0;
  const float2* Hp = (const float2*)Hm + (size_t)m * 512;
#pragma unroll
  for (int n = 0; n < 8; ++n) {
    const float2 h2v = Hp[n * 64 + k];
    hp = fma((double)h2v.x, (double)h2v.x, hp);
    hp = fma((double)h2v.y, (double)h2v.y, hp);
  }
  const double tp = wave_sum_f64(hp);
  double ypart = 0.0;
  if (k < 16) { const double yv = (double)y[m * 16 + k]; ypart = yv * yv; }
  const double yp = wave_sum_f64(ypart);

  const float2 vv = ((const float2*)v)[m * 64 + k];
  const float snrv = snr[m * 64 + k];
  const double hpm = hp_mean[b * 64 + k];

  double feat64[9];
  feat64[0] = (double)vv.x;
  feat64[1] = (double)vv.y;
  feat64[2] = (double)snrv;
  feat64[3] = hp;
  feat64[4] = hpm;
  feat64[5] = log1p(hp / ((tp - hp) + 1e-10));
  feat64[6] = log1p(tp);
  feat64[7] = log1p(yp);
  feat64[8] = sqrt(fma((double)vv.x, (double)vv.x,
                       fma((double)vv.y, (double)vv.y, 1e-10)));

  float feat32[9];
#pragma unroll
  for (int i = 0; i < 9; ++i) feat32[i] = (float)feat64[i];

  // ---- f32 MLP ----
  float h1[64], h2[64], h3[64];
  layer_relu64<9>(feat32, w1, b1, h1);
  layer_relu64<64>(h1, w2, b2, h2);
  layer_relu64<64>(h2, w3, b3, h3);
  float ly[6], lh[6], ld[6];
  head6(h3, wy, by, ly);
  head6(h3, wh, bh, lh);
  head6(h3, wd, bd, ld);

  const uint32_t g1k0 = keys[0], g1k1 = keys[1];
  const uint32_t g2k0 = keys[2], g2k1 = keys[3];
  const uint32_t g3k0 = keys[4], g3k1 = keys[5];

  // ---- gumbel-hard selections (tau>0 scales scores monotonically; skip) ----
  float uHv[6], uDv[6];
  double sH[6], sD[6];
  const uint32_t eH = (uint32_t)(m * 64 + k) * 6u;
#pragma unroll
  for (int j = 0; j < 6; ++j) {
    const float u = bits_to_unif(jax_randbits(g2k0, g2k1, eH + j, 6291456u));
    uHv[j] = u;
    sH[j] = (double)lh[j] + (double)(-logf(-logf(u)));
  }
#pragma unroll
  for (int j = 0; j < 6; ++j) {
    const float u = bits_to_unif(jax_randbits(g3k0, g3k1, eH + j, 6291456u));
    uDv[j] = u;
    sD[j] = (double)ld[j] + (double)(-logf(-logf(u)));
  }
  int argH, argD; double gapH, gapD;
  argmax_gap6(sH, argH, gapH);
  argmax_gap6(sD, argD, gapD);

  // logits_y mean over k (f64 reduction)
  double lysum[6];
#pragma unroll
  for (int j = 0; j < 6; ++j) lysum[j] = wave_sum_f64((double)ly[j]);

  int argY = 0; double gapY = 1e30;
  float uYv[6];
  if (k == 0) {
    double sY[6];
#pragma unroll
    for (int j = 0; j < 6; ++j) {
      const float u = bits_to_unif(jax_randbits(g1k0, g1k1, (uint32_t)(m * 6 + j), 98304u));
      uYv[j] = u;
      sY[j] = lysum[j] * (1.0 / 64.0) - log(-log((double)u));
    }
    argmax_gap6(sY, argY, gapY);
  }
  const int needY = __shfl((k == 0 && gapY < MARGIN_THETA) ? 1 : 0, 0);
  const bool needHD = (gapH < MARGIN_THETA) || (gapD < MARGIN_THETA);

  if (needHD || needY) {  // rare (~0.03% of lanes): full f64 recompute
    double f2[9];
#pragma unroll
    for (int i = 0; i < 9; ++i) f2[i] = feat64[i];
    double lyd[6], lhd[6], ldd[6];
    mlp_f64_fallback(f2, w1, b1, w2, b2, w3, b3, wy, by, wh, bh, wd, bd,
                     lyd, lhd, ldd);
    if (gapH < MARGIN_THETA) {
      double s2[6];
#pragma unroll
      for (int j = 0; j < 6; ++j) s2[j] = lhd[j] - log(-log((double)uHv[j]));
      double g; argmax_gap6(s2, argH, g);
    }
    if (gapD < MARGIN_THETA) {
      double s2[6];
#pragma unroll
      for (int j = 0; j < 6; ++j) s2[j] = ldd[j] - log(-log((double)uDv[j]));
      double g; argmax_gap6(s2, argD, g);
    }
    if (needY) {  // wave-uniform: all 64 lanes present here
      double lys2[6];
#pragma unroll
      for (int j = 0; j < 6; ++j) lys2[j] = wave_sum_f64(lyd[j]);
      if (k == 0) {
        double s2[6];
#pragma unroll
        for (int j = 0; j < 6; ++j)
          s2[j] = lys2[j] * (1.0 / 64.0) - log(-log((double)uYv[j]));
        double g; argmax_gap6(s2, argY, g);
      }
    }
  }
  argY = __shfl(argY, 0);

  // ---- outputs ----
  const float bY = 16.0f * idx_to_bits(argY);   // 2*N*bits
  const float bH = 16.0f * idx_to_bits(argH);
  const float bD = 2.0f * idx_to_bits(argD);

  if (k == 0) {
    out[O_yba + m] = bY;
#pragma unroll
    for (int j = 0; j < 6; ++j) out[O_wy + m * 6 + j] = (j == argY) ? 1.0f : 0.0f;
  }
  out[O_Hbl + (size_t)m * 64 + k] = bH;
  out[O_dbl + (size_t)m * 64 + k] = bD;
  out[O_eb + (size_t)m * 64 + k] = (bY * 0.015625f + bH) + bD;
#pragma unroll
  for (int j = 0; j < 6; ++j) {
    out[O_wH + (size_t)(m * 64 + k) * 6 + j] = (j == argH) ? 1.0f : 0.0f;
    out[O_wd + (size_t)(m * 64 + k) * 6 + j] = (j == argD) ? 1.0f : 0.0f;
  }
}

// ---------------------------------------------------------------- LSQ quant
__device__ __forceinline__ int bits_to_idx(int bits) {
  return (bits <= 8) ? ((bits >> 1) - 1) : ((bits == 12) ? 4 : 5);
}

__device__ __forceinline__ float lsq1(float x, float ssv, float qn, float qp) {
  float t = x / ssv;                 // IEEE f32 division, matches jnp
  t = fminf(fmaxf(t, qn), qp);       // clip
  return rintf(t) * ssv;             // round-half-even * ss
}

__global__ void k3_Hq(const float* __restrict__ Hm, const float* __restrict__ ss,
                      const float* __restrict__ Hbits, float* __restrict__ outHq) {
  const int id = blockIdx.x * blockDim.x + threadIdx.x;  // float2 elements
  if (id >= 8388608) return;
  const int k = id & 63;
  const int m = id >> 9;
  const int bits = (int)Hbits[(size_t)m * 64 + k] >> 4;
  const int i = bits_to_idx(bits);
  const float ssv = ss[6 + i];
  const float qp = (float)((1 << (bits - 1)) - 1);
  const float qn = -(float)(1 << (bits - 1));
  const float2 x = ((const float2*)Hm)[id];
  float2 o;
  o.x = lsq1(x.x, ssv, qn, qp);
  o.y = lsq1(x.y, ssv, qn, qp);
  ((float2*)outHq)[id] = o;
}

__global__ void k4_vq(const float* __restrict__ v, const float* __restrict__ ss,
                      const float* __restrict__ dbits, float* __restrict__ outvq) {
  const int id = blockIdx.x * blockDim.x + threadIdx.x;  // float2 = (m,k)
  if (id >= 1048576) return;
  const int bits = (int)dbits[id] >> 1;
  const int i = bits_to_idx(bits);
  const float ssv = ss[12 + i];
  const float qp = (float)((1 << (bits - 1)) - 1);
  const float qn = -(float)(1 << (bits - 1));
  const float2 x = ((const float2*)v)[id];
  float2 o;
  o.x = lsq1(x.x, ssv, qn, qp);
  o.y = lsq1(x.y, ssv, qn, qp);
  ((float2*)outvq)[id] = o;
}

__global__ void k5_yq(const float* __restrict__ y, const float* __restrict__ ss,
                      const float* __restrict__ ybits, float* __restrict__ outyq) {
  const int id = blockIdx.x * blockDim.x + threadIdx.x;  // float2 = (m,n)
  if (id >= 131072) return;
  const int m = id >> 3;
  const int bits = (int)ybits[m] >> 4;
  const int i = bits_to_idx(bits);
  const float ssv = ss[i];
  const float qp = (float)((1 << (bits - 1)) - 1);
  const float qn = -(float)(1 << (bits - 1));
  const float2 x = ((const float2*)y)[id];
  float2 o;
  o.x = lsq1(x.x, ssv, qn, qp);
  o.y = lsq1(x.y, ssv, qn, qp);
  ((float2*)outyq)[id] = o;
}

// ---------------------------------------------------------------- launch
extern "C" void kernel_launch(void* const* d_in, const int* in_sizes, int n_in,
                              void* d_out, int out_size, void* d_ws, size_t ws_size,
                              hipStream_t stream) {
  const float* v   = (const float*)d_in[0];
  const float* Hm  = (const float*)d_in[1];
  const float* y   = (const float*)d_in[2];
  const float* snr = (const float*)d_in[3];
  const float* w1  = (const float*)d_in[4];
  const float* b1  = (const float*)d_in[5];
  const float* w2  = (const float*)d_in[6];
  const float* b2  = (const float*)d_in[7];
  const float* w3  = (const float*)d_in[8];
  const float* b3  = (const float*)d_in[9];
  const float* wy  = (const float*)d_in[10];
  const float* by  = (const float*)d_in[11];
  const float* wh  = (const float*)d_in[12];
  const float* bh  = (const float*)d_in[13];
  const float* wd  = (const float*)d_in[14];
  const float* bd  = (const float*)d_in[15];
  const float* sy  = (const float*)d_in[16];
  const float* sH  = (const float*)d_in[17];
  const float* sd  = (const float*)d_in[18];
  // d_in[19] = tau (==1); argmax is invariant to tau>0 and y_soft cancels.

  float* out = (float*)d_out;

  // workspace layout (~289 KB): partial(32768 d) | hp_mean(4096 d) | ss(18 f) | keys(6 u32)
  double* ws_partial = (double*)d_ws;
  double* ws_hpmean  = ws_partial + 32768;
  float*  ws_ss      = (float*)(ws_hpmean + 4096);
  uint32_t* ws_keys  = (uint32_t*)(ws_ss + 18);

  k0_setup<<<1, 64, 0, stream>>>(sy, sH, sd, ws_ss, ws_keys);
  k1a_hpower_partial<<<512, 128, 0, stream>>>(Hm, ws_partial);
  k1b_hpmean<<<16, 256, 0, stream>>>(ws_partial, ws_hpmean);
  k2_main<<<BL, 64, 0, stream>>>(v, Hm, y, snr, w1, b1, w2, b2, w3, b3,
                                 wy, by, wh, bh, wd, bd, ws_hpmean, ws_keys, out);
  k3_Hq<<<32768, 256, 0, stream>>>(Hm, ws_ss, out + O_Hbl, out + O_Hq);
  k4_vq<<<4096, 256, 0, stream>>>(v, ws_ss, out + O_dbl, out + O_vq);
  k5_yq<<<512, 256, 0, stream>>>(y, ws_ss, out + O_yba, out + O_yq);
}